// Round 5
// baseline (179.273 us; speedup 1.0000x reference)
//
#include <hip/hip_runtime.h>
#include <hip/hip_bf16.h>
#include <math.h>

// Problem constants (B=8, T=1024, C=768, H=12, D=64)
#define BATCH 8
#define SEQ   1024
#define CH    768
#define NH    12
#define HD    64
#define HSZ   (BATCH * NH * SEQ * HD)   // 6291456 elements = B*T*C

typedef __attribute__((ext_vector_type(8))) short short8;   // 8 bf16 = 4 VGPRs
typedef __attribute__((ext_vector_type(4))) short short4v;
typedef __attribute__((ext_vector_type(4))) float floatx4;  // MFMA C/D frag

// fp32 -> bf16 RNE
static __device__ inline short f2bf(float f) {
    union { float f; unsigned u; } x; x.f = f;
    unsigned r = (x.u + 0x7fffu + ((x.u >> 16) & 1u)) >> 16;
    return (short)r;
}

// async global->LDS, 16B per lane; LDS dest must be wave-uniform base + lane*16
#define GLOAD_LDS16(g, l)                                                     \
    __builtin_amdgcn_global_load_lds(                                         \
        (const __attribute__((address_space(1))) void*)(g),                   \
        (__attribute__((address_space(3))) void*)(l), 16, 0, 0)

// raw barrier + manual waits for the phase schedule (no __syncthreads in loop)
#define BARF()  do { asm volatile("" ::: "memory");                           \
                     __builtin_amdgcn_s_barrier();                            \
                     asm volatile("" ::: "memory"); } while (0)
#define LGKM0()  asm volatile("s_waitcnt lgkmcnt(0)" ::: "memory")
#define VMCNT(N) asm volatile("s_waitcnt vmcnt(" #N ")" ::: "memory")
#define SCHED0() __builtin_amdgcn_sched_barrier(0)

// ---------------------------------------------------------------------------
// Fused prep (one launch): cast x fp32->bf16; transpose-cast w_attn and w_proj
// to bf16 [N,K]. Block role decoded from blockIdx.x.
// ---------------------------------------------------------------------------
#define NCAST (BATCH * SEQ * CH / 1024)          // 6144 blocks, 1024 elems each
#define NTA   ((3 * CH / 32) * (CH / 32))        // 1728 tiles for w_attn
#define NTP   ((CH / 32) * (CH / 32))            // 576 tiles for w_proj

__device__ __forceinline__ void transpose_tile(
    const float* __restrict__ w, short* __restrict__ wt, int K, int N,
    int bx, int by, int tid, float (*tile)[33])
{
    const int tx = tid & 31, ty = tid >> 5;      // 32 x 8
    const int n0 = bx * 32, k0 = by * 32;
    #pragma unroll
    for (int i = 0; i < 4; i++)
        tile[ty + i * 8][tx] = w[(size_t)(k0 + ty + i * 8) * N + n0 + tx];
    __syncthreads();
    #pragma unroll
    for (int i = 0; i < 4; i++)
        wt[(size_t)(n0 + ty + i * 8) * K + k0 + tx] = f2bf(tile[tx][ty + i * 8]);
}

__global__ __launch_bounds__(256) void prep_kernel(
    const float* __restrict__ x, short* __restrict__ xb,
    const float* __restrict__ wa, short* __restrict__ wta,
    const float* __restrict__ wp, short* __restrict__ wtp)
{
    __shared__ float tile[32][33];
    const int bid = blockIdx.x, tid = threadIdx.x;
    if (bid < NCAST) {
        int i = (bid * 256 + tid) * 4;
        float4 v = *(const float4*)(x + i);
        short4v o = { f2bf(v.x), f2bf(v.y), f2bf(v.z), f2bf(v.w) };
        *(short4v*)(xb + i) = o;
    } else if (bid < NCAST + NTA) {
        int t = bid - NCAST;
        transpose_tile(wa, wta, CH, 3 * CH, t % (3 * CH / 32), t / (3 * CH / 32), tid, tile);
    } else {
        int t = bid - NCAST - NTA;
        transpose_tile(wp, wtp, CH, CH, t % (CH / 32), t / (CH / 32), tid, tile);
    }
}

// ---------------------------------------------------------------------------
// GEMM1 (round-2 version, best measured 47.2 us): 256x192 bf16 MFMA GEMM for
// qkv with 4-phase COUNTED-vmcnt schedule (T4), double-buffered LDS.
//
// Load/read dependence structure (per K-tile, 7 cooperative chunk loads):
//   A chunks 0..3 = 64 rows each; B chunks 0..2.
//   Phases g=0,1 read A-chunks {0 (wm=0), 2 (wm=1)} + all B chunks.
//   Phases g=2,3 read A-chunks {1 (wm=0), 3 (wm=1)}.
// Issue order for tile t+1 (during tile t):
//   phase 0: B0,B1,B2   phase 1: A0,A2   phase 2: A1,A3
// Waits: end ph1 vmcnt(5) [retires prev A1,A3]; end ph3 vmcnt(2) [retires
// B0-2,A0,A2]. Never 0 in steady state; last tile vmcnt(0) at ph1 only.
// ---------------------------------------------------------------------------
__global__ __launch_bounds__(512, 2) void gemm1_8ph_kernel(
    const short* __restrict__ A, const short* __restrict__ Bt,
    const float* __restrict__ bias, short* __restrict__ qkv)
{
    const int K = CH;                         // 768
    __shared__ __align__(16) short smem[57344];   // 114688 B
    short* As = smem;                         // [2][256][64] bf16
    short* Bs = smem + 32768;                 // [2][192][64] bf16

    const int tid  = threadIdx.x;
    const int lane = tid & 63;
    const int col  = lane & 15;
    const int quad = lane >> 4;
    const int wave = tid >> 6;                // 0..7
    const int wm   = wave >> 2;               // 0..1
    const int wn   = wave & 3;                // 0..3

    const int bid = blockIdx.x;
    const int xcd = bid & 7;
    const int t8  = bid >> 3;                 // 0..47
    const int mb  = xcd * 4 + t8 / 12;        // 0..31
    const int nb  = t8 % 12;                  // 0..11
    const int m0  = mb * 256;
    const int n0  = nb * 192;

    // staging pointers: source pre-swizzled, LDS dest linear (rule #21)
    const int srow = tid >> 3;                // 0..63 (row within 64-row chunk)
    const int swz  = ((tid & 7) ^ (srow & 7)) << 3;   // swizzled 16B chunk, in shorts
    const short* aP[4];
    const short* bP[3];
    #pragma unroll
    for (int c = 0; c < 4; ++c)
        aP[c] = A + (size_t)(m0 + c * 64 + srow) * K + swz;
    #pragma unroll
    for (int c = 0; c < 3; ++c)
        bP[c] = Bt + (size_t)(n0 + c * 64 + srow) * K + swz;

    // fragment-read chunk offsets (row&7 == col&7 for all frag rows)
    const int cswz0 = ((quad) ^ (col & 7)) << 3;      // k-step s=0
    const int cswz1 = cswz0 ^ 32;                     // k-step s=1 (chunk ^ 4)
    const int aBase = (wm * 128 + col) * 64;
    const int bBase = (wn * 48 + col) * 64;

    floatx4 acc[8][3];
    #pragma unroll
    for (int i = 0; i < 8; ++i)
        #pragma unroll
        for (int j = 0; j < 3; ++j)
            acc[i][j] = (floatx4){0.f, 0.f, 0.f, 0.f};

    // prologue: stage tile 0 into buffer 0, in steady-state wait order
    GLOAD_LDS16(bP[0], &Bs[0 * 4096 + tid * 8]);
    GLOAD_LDS16(bP[1], &Bs[1 * 4096 + tid * 8]);
    GLOAD_LDS16(bP[2], &Bs[2 * 4096 + tid * 8]);
    GLOAD_LDS16(aP[0], &As[0 * 4096 + tid * 8]);
    GLOAD_LDS16(aP[2], &As[2 * 4096 + tid * 8]);
    GLOAD_LDS16(aP[1], &As[1 * 4096 + tid * 8]);
    GLOAD_LDS16(aP[3], &As[3 * 4096 + tid * 8]);
    VMCNT(2);                                 // B0-2, A0, A2 resident
    BARF();

    #pragma unroll 1
    for (int t = 0; t < 12; ++t) {            // 12 K-tiles of 64
        const int  P  = t & 1;
        const bool pf = (t < 11);
        const int  sk = (t + 1) * 64;
        const short* lA = As + P * 16384;
        const short* lB = Bs + P * 12288;
        short* wA = As + (P ^ 1) * 16384;
        short* wB = Bs + (P ^ 1) * 12288;

        short8 bf[3][2];                      // B frags live across the tile
        #pragma unroll
        for (int nt = 0; nt < 3; ++nt) {
            bf[nt][0] = *(const short8*)&lB[bBase + nt * 1024 + cswz0];
            bf[nt][1] = *(const short8*)&lB[bBase + nt * 1024 + cswz1];
        }

        #pragma unroll
        for (int g = 0; g < 4; ++g) {         // 4 phases, 2 m-frags each
            short8 af[2][2];
            #pragma unroll
            for (int dm = 0; dm < 2; ++dm) {
                const int ro = aBase + (g * 2 + dm) * 1024;
                af[dm][0] = *(const short8*)&lA[ro + cswz0];
                af[dm][1] = *(const short8*)&lA[ro + cswz1];
            }
            if (g == 0 && pf) {               // B chunks for t+1
                GLOAD_LDS16(bP[0] + sk, &wB[0 * 4096 + tid * 8]);
                GLOAD_LDS16(bP[1] + sk, &wB[1 * 4096 + tid * 8]);
                GLOAD_LDS16(bP[2] + sk, &wB[2 * 4096 + tid * 8]);
            }
            if (g == 1 && pf) {               // early A chunks for t+1
                GLOAD_LDS16(aP[0] + sk, &wA[0 * 4096 + tid * 8]);
                GLOAD_LDS16(aP[2] + sk, &wA[2 * 4096 + tid * 8]);
            }
            if (g == 2 && pf) {               // late A chunks for t+1
                GLOAD_LDS16(aP[1] + sk, &wA[1 * 4096 + tid * 8]);
                GLOAD_LDS16(aP[3] + sk, &wA[3 * 4096 + tid * 8]);
            }
            BARF();
            LGKM0();
            SCHED0();
            __builtin_amdgcn_s_setprio(1);
            #pragma unroll
            for (int s = 0; s < 2; ++s)
                #pragma unroll
                for (int dm = 0; dm < 2; ++dm)
                    #pragma unroll
                    for (int nt = 0; nt < 3; ++nt)
                        acc[g * 2 + dm][nt] = __builtin_amdgcn_mfma_f32_16x16x32_bf16(
                            af[dm][s], bf[nt][s], acc[g * 2 + dm][nt], 0, 0, 0);
            __builtin_amdgcn_s_setprio(0);
            if (g == 1) {                     // before phase-2 reads A1/A3
                if (pf) { VMCNT(5); } else { VMCNT(0); }
            }
            if (g == 3 && pf) { VMCNT(2); }   // before next tile-top reads
            BARF();
        }
    }

    // ---- coalesced q/k/v epilogue through (now-dead) LDS ----
    short* Es = smem;
    const int sel = nb >> 2;                  // 0=q, 1=k, 2=v (192 | 768)
    const int h0  = (nb & 3) * 3;             // first of 3 heads in this slice
    const int bb  = m0 >> 10;
    const int t0  = m0 & 1023;

    if (sel < 2) {
        // LDS [m][n], stride 200 (conflict-broken); 256x200 shorts = 102400 B
        #pragma unroll
        for (int nt = 0; nt < 3; ++nt) {
            const int ln = wn * 48 + nt * 16 + col;
            const float bv = bias[n0 + ln];
            #pragma unroll
            for (int mt = 0; mt < 8; ++mt)
                #pragma unroll
                for (int r = 0; r < 4; ++r) {
                    const int lm = wm * 128 + mt * 16 + quad * 4 + r;
                    Es[lm * 200 + ln] = f2bf(acc[mt][nt][r] + bv);
                }
        }
        BARF();
        // 8 lanes cover one 128B t-row; contiguous across lanes
        #pragma unroll
        for (int it = 0; it < 12; ++it) {
            const int id = it * 512 + tid;            // 0..6143 = 256 rows x 24 chunks
            const int lm = id / 24, c24 = id - lm * 24;
            const int hp = c24 >> 3, dc = c24 & 7;
            short8 v = *(const short8*)&Es[lm * 200 + hp * 64 + dc * 8];
            size_t dst = (size_t)sel * HSZ +
                (((size_t)(bb * NH + h0 + hp)) * SEQ + t0 + lm) * HD + dc * 8;
            *(short8*)&qkv[dst] = v;
        }
    } else {
        // v: LDS [n][m], stride 264; b64 packed writes (r-values m-adjacent)
        #pragma unroll
        for (int nt = 0; nt < 3; ++nt) {
            const int ln = wn * 48 + nt * 16 + col;
            const float bv = bias[n0 + ln];
            #pragma unroll
            for (int mt = 0; mt < 8; ++mt) {
                const int lm = wm * 128 + mt * 16 + quad * 4;
                short4v pk;
                #pragma unroll
                for (int r = 0; r < 4; ++r) pk[r] = f2bf(acc[mt][nt][r] + bv);
                *(short4v*)&Es[ln * 264 + lm] = pk;
            }
        }
        BARF();
        // 32 lanes cover 256 consecutive t per (h,d) row
        #pragma unroll
        for (int it = 0; it < 12; ++it) {
            const int id = it * 512 + tid;            // 0..6143 = 192 rows x 32 chunks
            const int ln = id >> 5, tc = id & 31;
            short8 v = *(const short8*)&Es[ln * 264 + tc * 8];
            const int hp = ln >> 6, d = ln & 63;
            size_t dst = (size_t)2 * HSZ +
                (((size_t)(bb * NH + h0 + hp)) * HD + d) * SEQ + t0 + tc * 8;
            *(short8*)&qkv[dst] = v;
        }
    }
}

// ---------------------------------------------------------------------------
// bf16 MFMA GEMM (2-phase structure) — used for GEMM2 (MODE 0).
// ---------------------------------------------------------------------------
template <int MODE, int BM, int BN, int NBLK, int MBX, int WPE>
__global__ __launch_bounds__(256, WPE) void gemm_bt_kernel(
    const short* __restrict__ A, const short* __restrict__ Bt,
    const float* __restrict__ bias, void* __restrict__ outv,
    int M, int N, int K)
{
    constexpr int MT  = BM / 32;
    constexpr int NT  = BN / 32;
    constexpr int ACH = BM / 64;
    constexpr int BCH = BN / 64;
    constexpr int LDS_BYTES = (BM + BN) * 128;    // 2 bufs x rows x 64B
    __shared__ __align__(16) char smem[LDS_BYTES];
    short* AsB = (short*)smem;                    // 2 bufs x BM*32
    short* BsB = (short*)(smem + BM * 128);       // 2 bufs x BN*32

    const int tid  = threadIdx.x;
    const int lane = tid & 63;
    const int col  = lane & 15;
    const int quad = lane >> 4;
    const int wave = tid >> 6;
    const int wm = wave & 1, wn = wave >> 1;

    const int bid = blockIdx.x;
    const int j   = bid & 7;
    const int t   = bid >> 3;
    const int mb  = j * MBX + t / NBLK;
    const int nb  = t % NBLK;
    const int m0 = mb * BM, n0 = nb * BN;

    const int srow = tid >> 2;
    const int kc   = ((tid & 3) ^ (srow & 3)) * 8;
    const short* aptr[ACH];
    const short* bptr[BCH];
    #pragma unroll
    for (int c = 0; c < ACH; c++)
        aptr[c] = A + (size_t)(m0 + c * 64 + srow) * K + kc;
    #pragma unroll
    for (int c = 0; c < BCH; c++)
        bptr[c] = Bt + (size_t)(n0 + c * 64 + srow) * K + kc;

    floatx4 acc[MT][NT];
    #pragma unroll
    for (int i = 0; i < MT; i++)
        #pragma unroll
        for (int jj = 0; jj < NT; jj++)
            acc[i][jj] = (floatx4){0.f, 0.f, 0.f, 0.f};

    const int niter = K / 32;

    #pragma unroll
    for (int c = 0; c < ACH; c++) GLOAD_LDS16(aptr[c], &AsB[c * 2048 + tid * 8]);
    #pragma unroll
    for (int c = 0; c < BCH; c++) GLOAD_LDS16(bptr[c], &BsB[c * 2048 + tid * 8]);

    for (int k = 0; k < niter; k++) {
        __syncthreads();
        const int cur = k & 1, nxt = cur ^ 1;
        if (k + 1 < niter) {
            const int ko = (k + 1) * 32;
            #pragma unroll
            for (int c = 0; c < ACH; c++)
                GLOAD_LDS16(aptr[c] + ko, &AsB[nxt * BM * 32 + c * 2048 + tid * 8]);
            #pragma unroll
            for (int c = 0; c < BCH; c++)
                GLOAD_LDS16(bptr[c] + ko, &BsB[nxt * BN * 32 + c * 2048 + tid * 8]);
        }
        short8 af[MT], bf[NT];
        #pragma unroll
        for (int mt = 0; mt < MT; mt++) {
            const int row = wm * (BM / 2) + mt * 16 + col;
            af[mt] = *(const short8*)&AsB[cur * BM * 32 + row * 32 + ((quad ^ (row & 3)) << 3)];
        }
        #pragma unroll
        for (int nt = 0; nt < NT; nt++) {
            const int row = wn * (BN / 2) + nt * 16 + col;
            bf[nt] = *(const short8*)&BsB[cur * BN * 32 + row * 32 + ((quad ^ (row & 3)) << 3)];
        }
        #pragma unroll
        for (int mt = 0; mt < MT; mt++)
            #pragma unroll
            for (int nt = 0; nt < NT; nt++)
                acc[mt][nt] = __builtin_amdgcn_mfma_f32_16x16x32_bf16(
                    af[mt], bf[nt], acc[mt][nt], 0, 0, 0);
    }

    // fp32 row-major store (already reasonably coalesced)
    #pragma unroll
    for (int mt = 0; mt < MT; mt++) {
        #pragma unroll
        for (int r = 0; r < 4; r++) {
            const int m = m0 + wm * (BM / 2) + mt * 16 + quad * 4 + r;
            #pragma unroll
            for (int nt = 0; nt < NT; nt++) {
                const int n = n0 + wn * (BN / 2) + nt * 16 + col;
                ((float*)outv)[(size_t)m * N + n] = acc[mt][nt][r] + bias[n];
            }
        }
    }
}

// ---------------------------------------------------------------------------
// bf16 MFMA flash attention (unchanged):
//  - 128-row Q tiles, 2 strips/wave, fixed-shift softmax (no online max),
//    l via ones-MFMA, truncating P stores, heavy-first dispatch.
// ---------------------------------------------------------------------------
#define LDK 72   // padded row length (bf16) -> 144 B stride

template <bool DIAG>
__device__ __forceinline__ void strip_step(
    const short* __restrict__ Ksh, const short* __restrict__ Vsh,
    short* __restrict__ pw, const short8* aq, floatx4* acc_o,
    floatx4& lacc, short8 bones, int col, int quad, int qrow0)
{
    floatx4 sacc[4];
    #pragma unroll
    for (int i = 0; i < 4; i++) sacc[i] = (floatx4){0.f, 0.f, 0.f, 0.f};
    #pragma unroll
    for (int s = 0; s < 2; s++)
        #pragma unroll
        for (int nt = 0; nt < 4; nt++) {
            short8 bk = *(const short8*)&Ksh[(nt * 16 + col) * LDK + s * 32 + quad * 8];
            sacc[nt] = __builtin_amdgcn_mfma_f32_16x16x32_bf16(aq[s], bk, sacc[nt], 0, 0, 0);
        }

    const float SCL = 0.18033688011112042f;   // 0.125 * log2(e)
    #pragma unroll
    for (int r = 0; r < 4; r++)
        #pragma unroll
        for (int nt = 0; nt < 4; nt++) {
            float sv = sacc[nt][r] * SCL;
            if (DIAG && (nt * 16 + col) > (qrow0 + r)) sv = -INFINITY;
            float pv = __builtin_amdgcn_exp2f(sv);
            pw[(quad * 4 + r) * LDK + nt * 16 + col] =
                (short)(__builtin_bit_cast(unsigned, pv) >> 16);
        }
    __builtin_amdgcn_wave_barrier();

    short8 ap[2];
    ap[0] = *(const short8*)&pw[col * LDK + quad * 8];
    ap[1] = *(const short8*)&pw[col * LDK + 32 + quad * 8];

    #pragma unroll
    for (int s = 0; s < 2; s++) {
        #pragma unroll
        for (int nt = 0; nt < 4; nt++) {
            short8 bv = *(const short8*)&Vsh[(nt * 16 + col) * LDK + s * 32 + quad * 8];
            acc_o[nt] = __builtin_amdgcn_mfma_f32_16x16x32_bf16(ap[s], bv, acc_o[nt], 0, 0, 0);
        }
        lacc = __builtin_amdgcn_mfma_f32_16x16x32_bf16(ap[s], bones, lacc, 0, 0, 0);
    }
}

__global__ __launch_bounds__(256, 3) void attn_kernel(
    const short* __restrict__ Qg, const short* __restrict__ Kg,
    const short* __restrict__ Vg, short* __restrict__ Y)
{
    __shared__ __align__(16) short Ksh[64 * LDK];
    __shared__ __align__(16) short Vsh[64 * LDK];        // [dim][key]
    __shared__ __align__(16) short Psh[4][2][16 * LDK];  // per-wave, per-strip

    const int tid  = threadIdx.x;
    const int wave = tid >> 6;
    const int lane = tid & 63;
    const int col  = lane & 15;
    const int quad = lane >> 4;
    const int bh = blockIdx.x;               // 0..95
    const int qt = 7 - blockIdx.y;           // 128-row q-tile, heavy-first
    const int b = bh / NH, h = bh - b * NH;

    const size_t kqbase = (size_t)bh * SEQ * HD;   // q,k: [bh][t][d]
    const size_t vbase  = (size_t)bh * HD * SEQ;   // v:   [bh][d][t]

    short8 aq[2][2];
    #pragma unroll
    for (int st = 0; st < 2; st++) {
        const short* qp = Qg + kqbase +
            (size_t)(qt * 128 + st * 64 + wave * 16 + col) * HD + quad * 8;
        aq[st][0] = *(const short8*)(qp);
        aq[st][1] = *(const short8*)(qp + 32);
    }

    floatx4 acc_o[2][4];
    floatx4 lacc[2];
    #pragma unroll
    for (int st = 0; st < 2; st++) {
        lacc[st] = (floatx4){0.f, 0.f, 0.f, 0.f};
        #pragma unroll
        for (int i = 0; i < 4; i++) acc_o[st][i] = (floatx4){0.f, 0.f, 0.f, 0.f};
    }

    const short one_bf = (short)0x3F80;
    short8 bones = (col == 0)
        ? (short8){one_bf, one_bf, one_bf, one_bf, one_bf, one_bf, one_bf, one_bf}
        : (short8){0, 0, 0, 0, 0, 0, 0, 0};

    const int qrow0 = wave * 16 + quad * 4;

    const int idx0 = tid * 8, idx1 = (256 + tid) * 8;
    const int row0 = idx0 >> 6, offs0 = idx0 & 63;
    const int row1 = idx1 >> 6, offs1 = idx1 & 63;

    short8 kreg[2], vreg[2];
    {
        const short* ksrc = Kg + kqbase;
        const short* vsrc = Vg + vbase;
        kreg[0] = *(const short8*)&ksrc[idx0];
        kreg[1] = *(const short8*)&ksrc[idx1];
        vreg[0] = *(const short8*)&vsrc[(size_t)row0 * SEQ + offs0];
        vreg[1] = *(const short8*)&vsrc[(size_t)row1 * SEQ + offs1];
    }

    const int nkt = 2 * qt + 2;
    for (int kt = 0; kt < nkt; kt++) {
        __syncthreads();
        *(short8*)&Ksh[row0 * LDK + offs0] = kreg[0];
        *(short8*)&Ksh[row1 * LDK + offs1] = kreg[1];
        *(short8*)&Vsh[row0 * LDK + offs0] = vreg[0];
        *(short8*)&Vsh[row1 * LDK + offs1] = vreg[1];
        __syncthreads();

        if (kt + 1 < nkt) {
            const short* ksrc = Kg + kqbase + (size_t)(kt + 1) * 64 * HD;
            const short* vsrc = Vg + vbase + (kt + 1) * 64;
            kreg[0] = *(const short8*)&ksrc[idx0];
            kreg[1] = *(const short8*)&ksrc[idx1];
            vreg[0] = *(const short8*)&vsrc[(size_t)row0 * SEQ + offs0];
            vreg[1] = *(const short8*)&vsrc[(size_t)row1 * SEQ + offs1];
        }

        if (kt < 2 * qt) {
            strip_step<false>(Ksh, Vsh, Psh[wave][0], aq[0], acc_o[0], lacc[0],
                              bones, col, quad, qrow0);
            strip_step<false>(Ksh, Vsh, Psh[wave][1], aq[1], acc_o[1], lacc[1],
                              bones, col, quad, qrow0);
        } else if (kt == 2 * qt) {
            strip_step<true>(Ksh, Vsh, Psh[wave][0], aq[0], acc_o[0], lacc[0],
                             bones, col, quad, qrow0);
            strip_step<false>(Ksh, Vsh, Psh[wave][1], aq[1], acc_o[1], lacc[1],
                              bones, col, quad, qrow0);
        } else {
            strip_step<true>(Ksh, Vsh, Psh[wave][1], aq[1], acc_o[1], lacc[1],
                             bones, col, quad, qrow0);
        }
    }

    #pragma unroll
    for (int st = 0; st < 2; st++) {
        #pragma unroll
        for (int r = 0; r < 4; r++) {
            float l = __shfl(lacc[st][r], quad * 16, 64);
            float inv = 1.f / l;
            int t = qt * 128 + st * 64 + wave * 16 + quad * 4 + r;
            size_t ybase = ((size_t)(b * SEQ + t)) * CH + h * HD;
            #pragma unroll
            for (int nt = 0; nt < 4; nt++)
                Y[ybase + nt * 16 + col] = f2bf(acc_o[st][nt][r] * inv);
        }
    }
}

// ---------------------------------------------------------------------------
extern "C" void kernel_launch(void* const* d_in, const int* in_sizes, int n_in,
                              void* d_out, int out_size, void* d_ws, size_t ws_size,
                              hipStream_t stream)
{
    const float* x      = (const float*)d_in[0];  // [B,T,C]
    const float* w_attn = (const float*)d_in[1];  // [C,3C]
    const float* b_attn = (const float*)d_in[2];  // [3C]
    const float* w_proj = (const float*)d_in[3];  // [C,C]
    const float* b_proj = (const float*)d_in[4];  // [C]
    float* out = (float*)d_out;                   // [B,T,C] fp32

    // workspace layout (bf16 shorts)
    short* qkv16 = (short*)d_ws;                          // 3*HSZ
    short* y16   = qkv16 + (size_t)3 * HSZ;               // HSZ   [B,T,C]
    short* xb    = y16   + (size_t)HSZ;                   // HSZ   [B*T, C]
    short* wta   = xb    + (size_t)HSZ;                   // [3C, C] = w_attn^T
    short* wtp   = wta   + (size_t)3 * CH * CH;           // [C, C]  = w_proj^T

    const int M = BATCH * SEQ;   // 8192

    // Fused prep: cast x + transpose-cast both weights (one launch)
    prep_kernel<<<NCAST + NTA + NTP, 256, 0, stream>>>(x, xb, w_attn, wta, w_proj, wtp);

    // GEMM1: qkv = x @ w_attn + b_attn -> bf16 q/k/v (v transposed)
    // round-2 counted-vmcnt schedule (best measured 47.2 us); grid 384
    gemm1_8ph_kernel<<<384, 512, 0, stream>>>(xb, wta, b_attn, qkv16);

    // Flash attention -> y16 bf16 [B,T,C]; 128-row q-tiles, heavy-first
    dim3 ga(BATCH * NH, SEQ / 128);    // (96, 8) = 768 blocks
    attn_kernel<<<ga, 256, 0, stream>>>(qkv16, qkv16 + (size_t)HSZ,
                                        qkv16 + (size_t)2 * HSZ, y16);

    // GEMM2: out = y @ w_proj + b_proj (fp32 out)
    // NEW: 128x192 tiles (proven 595-TF config as round-0 GEMM1).
    // grid = 8 xcd * 8 m * 4 n = 256 = exactly 1 block/CU, fully co-resident.
    gemm_bt_kernel<0, 128, 192, 4, 8, 3><<<256, 256, 0, stream>>>(
        y16, wtp, b_proj, out, M, CH, CH);
}

// Round 6
// 175.519 us; speedup vs baseline: 1.0214x; 1.0214x over previous
//
#include <hip/hip_runtime.h>
#include <hip/hip_bf16.h>
#include <math.h>

// Problem constants (B=8, T=1024, C=768, H=12, D=64)
#define BATCH 8
#define SEQ   1024
#define CH    768
#define NH    12
#define HD    64
#define HSZ   (BATCH * NH * SEQ * HD)   // 6291456 elements = B*T*C

typedef __attribute__((ext_vector_type(8))) short short8;   // 8 bf16 = 4 VGPRs
typedef __attribute__((ext_vector_type(4))) short short4v;
typedef __attribute__((ext_vector_type(4))) float floatx4;  // MFMA C/D frag

// fp32 -> bf16 RNE
static __device__ inline short f2bf(float f) {
    union { float f; unsigned u; } x; x.f = f;
    unsigned r = (x.u + 0x7fffu + ((x.u >> 16) & 1u)) >> 16;
    return (short)r;
}

// async global->LDS, 16B per lane; LDS dest must be wave-uniform base + lane*16
#define GLOAD_LDS16(g, l)                                                     \
    __builtin_amdgcn_global_load_lds(                                         \
        (const __attribute__((address_space(1))) void*)(g),                   \
        (__attribute__((address_space(3))) void*)(l), 16, 0, 0)

// ---------------------------------------------------------------------------
// Fused prep (one launch): cast x fp32->bf16; transpose-cast w_attn and w_proj
// to bf16 [N,K]. Block role decoded from blockIdx.x.
// ---------------------------------------------------------------------------
#define NCAST (BATCH * SEQ * CH / 1024)          // 6144 blocks, 1024 elems each
#define NTA   ((3 * CH / 32) * (CH / 32))        // 1728 tiles for w_attn
#define NTP   ((CH / 32) * (CH / 32))            // 576 tiles for w_proj

__device__ __forceinline__ void transpose_tile(
    const float* __restrict__ w, short* __restrict__ wt, int K, int N,
    int bx, int by, int tid, float (*tile)[33])
{
    const int tx = tid & 31, ty = tid >> 5;      // 32 x 8
    const int n0 = bx * 32, k0 = by * 32;
    #pragma unroll
    for (int i = 0; i < 4; i++)
        tile[ty + i * 8][tx] = w[(size_t)(k0 + ty + i * 8) * N + n0 + tx];
    __syncthreads();
    #pragma unroll
    for (int i = 0; i < 4; i++)
        wt[(size_t)(n0 + ty + i * 8) * K + k0 + tx] = f2bf(tile[tx][ty + i * 8]);
}

__global__ __launch_bounds__(256) void prep_kernel(
    const float* __restrict__ x, short* __restrict__ xb,
    const float* __restrict__ wa, short* __restrict__ wta,
    const float* __restrict__ wp, short* __restrict__ wtp)
{
    __shared__ float tile[32][33];
    const int bid = blockIdx.x, tid = threadIdx.x;
    if (bid < NCAST) {
        int i = (bid * 256 + tid) * 4;
        float4 v = *(const float4*)(x + i);
        short4v o = { f2bf(v.x), f2bf(v.y), f2bf(v.z), f2bf(v.w) };
        *(short4v*)(xb + i) = o;
    } else if (bid < NCAST + NTA) {
        int t = bid - NCAST;
        transpose_tile(wa, wta, CH, 3 * CH, t % (3 * CH / 32), t / (3 * CH / 32), tid, tile);
    } else {
        int t = bid - NCAST - NTA;
        transpose_tile(wp, wtp, CH, CH, t % (CH / 32), t / (CH / 32), tid, tile);
    }
}

// ---------------------------------------------------------------------------
// bf16 MFMA GEMM (round-0 structure — best measured TOTAL, 170.2 us):
// C[M,N] = A[M,K] @ Bt[N,K]^T + bias[N]
//  - K-loop: global_load_lds dbuf, 1 __syncthreads per K-tile of 32,
//    XOR bank swizzle, XCD-partitioned 1D grid.
//  - MODE 1: coalesced q/k/v epilogue through LDS (q/k [bh][t][d],
//    v [bh][d][t]).  MODE 0: fp32 row-major store.
// ---------------------------------------------------------------------------
template <int MODE, int BM, int BN, int NBLK, int MBX, int WPE>
__global__ __launch_bounds__(256, WPE) void gemm_bt_kernel(
    const short* __restrict__ A, const short* __restrict__ Bt,
    const float* __restrict__ bias, void* __restrict__ outv,
    int M, int N, int K)
{
    constexpr int MT  = BM / 32;
    constexpr int NT  = BN / 32;
    constexpr int ACH = BM / 64;
    constexpr int BCH = BN / 64;
    constexpr int STAGE_BYTES = (BM + BN) * 128;              // 2 bufs x rows x 64B
    constexpr int EPI_BYTES   = (MODE == 1) ? (BN * 136 * 2) : 0;  // v layout largest
    constexpr int LDS_BYTES   = STAGE_BYTES > EPI_BYTES ? STAGE_BYTES : EPI_BYTES;
    __shared__ __align__(16) char smem[LDS_BYTES];
    short* AsB = (short*)smem;                    // 2 bufs x BM*32
    short* BsB = (short*)(smem + BM * 128);       // 2 bufs x BN*32

    const int tid  = threadIdx.x;
    const int lane = tid & 63;
    const int col  = lane & 15;
    const int quad = lane >> 4;
    const int wave = tid >> 6;
    const int wm = wave & 1, wn = wave >> 1;

    const int bid = blockIdx.x;
    const int j   = bid & 7;
    const int t   = bid >> 3;
    const int mb  = j * MBX + t / NBLK;
    const int nb  = t % NBLK;
    const int m0 = mb * BM, n0 = nb * BN;

    const int srow = tid >> 2;
    const int kc   = ((tid & 3) ^ (srow & 3)) * 8;
    const short* aptr[ACH];
    const short* bptr[BCH];
    #pragma unroll
    for (int c = 0; c < ACH; c++)
        aptr[c] = A + (size_t)(m0 + c * 64 + srow) * K + kc;
    #pragma unroll
    for (int c = 0; c < BCH; c++)
        bptr[c] = Bt + (size_t)(n0 + c * 64 + srow) * K + kc;

    floatx4 acc[MT][NT];
    #pragma unroll
    for (int i = 0; i < MT; i++)
        #pragma unroll
        for (int jj = 0; jj < NT; jj++)
            acc[i][jj] = (floatx4){0.f, 0.f, 0.f, 0.f};

    const int niter = K / 32;

    #pragma unroll
    for (int c = 0; c < ACH; c++) GLOAD_LDS16(aptr[c], &AsB[c * 2048 + tid * 8]);
    #pragma unroll
    for (int c = 0; c < BCH; c++) GLOAD_LDS16(bptr[c], &BsB[c * 2048 + tid * 8]);

    for (int k = 0; k < niter; k++) {
        __syncthreads();
        const int cur = k & 1, nxt = cur ^ 1;
        if (k + 1 < niter) {
            const int ko = (k + 1) * 32;
            #pragma unroll
            for (int c = 0; c < ACH; c++)
                GLOAD_LDS16(aptr[c] + ko, &AsB[nxt * BM * 32 + c * 2048 + tid * 8]);
            #pragma unroll
            for (int c = 0; c < BCH; c++)
                GLOAD_LDS16(bptr[c] + ko, &BsB[nxt * BN * 32 + c * 2048 + tid * 8]);
        }
        short8 af[MT], bf[NT];
        #pragma unroll
        for (int mt = 0; mt < MT; mt++) {
            const int row = wm * (BM / 2) + mt * 16 + col;
            af[mt] = *(const short8*)&AsB[cur * BM * 32 + row * 32 + ((quad ^ (row & 3)) << 3)];
        }
        #pragma unroll
        for (int nt = 0; nt < NT; nt++) {
            const int row = wn * (BN / 2) + nt * 16 + col;
            bf[nt] = *(const short8*)&BsB[cur * BN * 32 + row * 32 + ((quad ^ (row & 3)) << 3)];
        }
        #pragma unroll
        for (int mt = 0; mt < MT; mt++)
            #pragma unroll
            for (int nt = 0; nt < NT; nt++)
                acc[mt][nt] = __builtin_amdgcn_mfma_f32_16x16x32_bf16(
                    af[mt], bf[nt], acc[mt][nt], 0, 0, 0);
    }

    if constexpr (MODE == 0) {
        // fp32 row-major store (already reasonably coalesced)
        #pragma unroll
        for (int mt = 0; mt < MT; mt++) {
            #pragma unroll
            for (int r = 0; r < 4; r++) {
                const int m = m0 + wm * (BM / 2) + mt * 16 + quad * 4 + r;
                #pragma unroll
                for (int nt = 0; nt < NT; nt++) {
                    const int n = n0 + wn * (BN / 2) + nt * 16 + col;
                    ((float*)outv)[(size_t)m * N + n] = acc[mt][nt][r] + bias[n];
                }
            }
        }
    } else {
        // coalesced q/k/v epilogue through LDS
        __syncthreads();                      // staging LDS now reusable
        short* Es = (short*)smem;
        const int sel = n0 / CH;              // uniform per block (192 | 768)
        const int h0  = (n0 - sel * CH) >> 6; // first head of this 3-head slice
        const int bb  = m0 >> 10;
        const int t0  = m0 & 1023;
        short* qkv = (short*)outv;

        if (sel < 2) {
            // LDS [m][n], stride 200 (conflict-broken)
            #pragma unroll
            for (int mt = 0; mt < MT; mt++)
                #pragma unroll
                for (int r = 0; r < 4; r++) {
                    const int lm = wm * (BM / 2) + mt * 16 + quad * 4 + r;
                    #pragma unroll
                    for (int nt = 0; nt < NT; nt++) {
                        const int ln = wn * (BN / 2) + nt * 16 + col;
                        Es[lm * 200 + ln] = f2bf(acc[mt][nt][r] + bias[n0 + ln]);
                    }
                }
            __syncthreads();
            // store: 8 lanes cover one 128B t-row; contiguous across lanes
            #pragma unroll
            for (int it = 0; it < (BM * BN / 8) / 256; it++) {
                const int id = it * 256 + tid;
                const int hp = id >> 10, lm = (id >> 3) & 127, dc = id & 7;
                short8 v = *(const short8*)&Es[lm * 200 + hp * 64 + dc * 8];
                size_t dst = (size_t)sel * HSZ +
                    (((size_t)(bb * NH + h0 + hp)) * SEQ + t0 + lm) * HD + dc * 8;
                *(short8*)&qkv[dst] = v;
            }
        } else {
            // v: LDS [n][m], stride 136; b64 packed writes (r-values m-adjacent)
            #pragma unroll
            for (int nt = 0; nt < NT; nt++) {
                const int ln = wn * (BN / 2) + nt * 16 + col;
                const float bv = bias[n0 + ln];
                #pragma unroll
                for (int mt = 0; mt < MT; mt++) {
                    const int lm = wm * (BM / 2) + mt * 16 + quad * 4;
                    short4v pk;
                    #pragma unroll
                    for (int r = 0; r < 4; r++) pk[r] = f2bf(acc[mt][nt][r] + bv);
                    *(short4v*)&Es[ln * 136 + lm] = pk;
                }
            }
            __syncthreads();
            // store: 16 lanes cover 128 consecutive t per (h,d) row
            #pragma unroll
            for (int it = 0; it < (BM * BN / 8) / 256; it++) {
                const int id = it * 256 + tid;
                const int ln = id >> 4, tc = id & 15;
                short8 v = *(const short8*)&Es[ln * 136 + tc * 8];
                const int hp = ln >> 6, d = ln & 63;
                size_t dst = (size_t)2 * HSZ +
                    (((size_t)(bb * NH + h0 + hp)) * HD + d) * SEQ + t0 + tc * 8;
                *(short8*)&qkv[dst] = v;
            }
        }
    }
}

// ---------------------------------------------------------------------------
// bf16 MFMA flash attention:
//  - 128-row Q tiles, 2 strips/wave, fixed-shift softmax (no online max),
//    l via ones-MFMA, truncating P stores.
//  - NEW (round 6): 1-D grid, bid = qt*96 + bh. Same-bh blocks differ by
//    96 = 0 (mod 8) -> round-robin puts all 8 q-tiles of one (b,h) on the
//    SAME XCD; per-XCD K/V footprint 12 bh x 256 KB = 3 MB < 4 MB L2, so
//    7 of 8 K/V re-reads become L2 hits instead of HBM traffic (T1 regime:
//    HBM-bound with inter-block operand reuse).
// ---------------------------------------------------------------------------
#define LDK 72   // padded row length (bf16) -> 144 B stride

template <bool DIAG>
__device__ __forceinline__ void strip_step(
    const short* __restrict__ Ksh, const short* __restrict__ Vsh,
    short* __restrict__ pw, const short8* aq, floatx4* acc_o,
    floatx4& lacc, short8 bones, int col, int quad, int qrow0)
{
    floatx4 sacc[4];
    #pragma unroll
    for (int i = 0; i < 4; i++) sacc[i] = (floatx4){0.f, 0.f, 0.f, 0.f};
    #pragma unroll
    for (int s = 0; s < 2; s++)
        #pragma unroll
        for (int nt = 0; nt < 4; nt++) {
            short8 bk = *(const short8*)&Ksh[(nt * 16 + col) * LDK + s * 32 + quad * 8];
            sacc[nt] = __builtin_amdgcn_mfma_f32_16x16x32_bf16(aq[s], bk, sacc[nt], 0, 0, 0);
        }

    const float SCL = 0.18033688011112042f;   // 0.125 * log2(e)
    #pragma unroll
    for (int r = 0; r < 4; r++)
        #pragma unroll
        for (int nt = 0; nt < 4; nt++) {
            float sv = sacc[nt][r] * SCL;
            if (DIAG && (nt * 16 + col) > (qrow0 + r)) sv = -INFINITY;
            float pv = __builtin_amdgcn_exp2f(sv);
            pw[(quad * 4 + r) * LDK + nt * 16 + col] =
                (short)(__builtin_bit_cast(unsigned, pv) >> 16);
        }
    __builtin_amdgcn_wave_barrier();

    short8 ap[2];
    ap[0] = *(const short8*)&pw[col * LDK + quad * 8];
    ap[1] = *(const short8*)&pw[col * LDK + 32 + quad * 8];

    #pragma unroll
    for (int s = 0; s < 2; s++) {
        #pragma unroll
        for (int nt = 0; nt < 4; nt++) {
            short8 bv = *(const short8*)&Vsh[(nt * 16 + col) * LDK + s * 32 + quad * 8];
            acc_o[nt] = __builtin_amdgcn_mfma_f32_16x16x32_bf16(ap[s], bv, acc_o[nt], 0, 0, 0);
        }
        lacc = __builtin_amdgcn_mfma_f32_16x16x32_bf16(ap[s], bones, lacc, 0, 0, 0);
    }
}

__global__ __launch_bounds__(256, 3) void attn_kernel(
    const short* __restrict__ Qg, const short* __restrict__ Kg,
    const short* __restrict__ Vg, short* __restrict__ Y)
{
    __shared__ __align__(16) short Ksh[64 * LDK];
    __shared__ __align__(16) short Vsh[64 * LDK];        // [dim][key]
    __shared__ __align__(16) short Psh[4][2][16 * LDK];  // per-wave, per-strip

    const int tid  = threadIdx.x;
    const int wave = tid >> 6;
    const int lane = tid & 63;
    const int col  = lane & 15;
    const int quad = lane >> 4;
    const int bid = blockIdx.x;              // 0..767
    const int bh  = bid % 96;                // XCD = bh & 7 for ALL q-tiles of bh
    const int qt  = bid / 96;                // 128-row q-tile
    const int b = bh / NH, h = bh - b * NH;

    const size_t kqbase = (size_t)bh * SEQ * HD;   // q,k: [bh][t][d]
    const size_t vbase  = (size_t)bh * HD * SEQ;   // v:   [bh][d][t]

    short8 aq[2][2];
    #pragma unroll
    for (int st = 0; st < 2; st++) {
        const short* qp = Qg + kqbase +
            (size_t)(qt * 128 + st * 64 + wave * 16 + col) * HD + quad * 8;
        aq[st][0] = *(const short8*)(qp);
        aq[st][1] = *(const short8*)(qp + 32);
    }

    floatx4 acc_o[2][4];
    floatx4 lacc[2];
    #pragma unroll
    for (int st = 0; st < 2; st++) {
        lacc[st] = (floatx4){0.f, 0.f, 0.f, 0.f};
        #pragma unroll
        for (int i = 0; i < 4; i++) acc_o[st][i] = (floatx4){0.f, 0.f, 0.f, 0.f};
    }

    const short one_bf = (short)0x3F80;
    short8 bones = (col == 0)
        ? (short8){one_bf, one_bf, one_bf, one_bf, one_bf, one_bf, one_bf, one_bf}
        : (short8){0, 0, 0, 0, 0, 0, 0, 0};

    const int qrow0 = wave * 16 + quad * 4;

    const int idx0 = tid * 8, idx1 = (256 + tid) * 8;
    const int row0 = idx0 >> 6, offs0 = idx0 & 63;
    const int row1 = idx1 >> 6, offs1 = idx1 & 63;

    short8 kreg[2], vreg[2];
    {
        const short* ksrc = Kg + kqbase;
        const short* vsrc = Vg + vbase;
        kreg[0] = *(const short8*)&ksrc[idx0];
        kreg[1] = *(const short8*)&ksrc[idx1];
        vreg[0] = *(const short8*)&vsrc[(size_t)row0 * SEQ + offs0];
        vreg[1] = *(const short8*)&vsrc[(size_t)row1 * SEQ + offs1];
    }

    const int nkt = 2 * qt + 2;
    for (int kt = 0; kt < nkt; kt++) {
        __syncthreads();
        *(short8*)&Ksh[row0 * LDK + offs0] = kreg[0];
        *(short8*)&Ksh[row1 * LDK + offs1] = kreg[1];
        *(short8*)&Vsh[row0 * LDK + offs0] = vreg[0];
        *(short8*)&Vsh[row1 * LDK + offs1] = vreg[1];
        __syncthreads();

        if (kt + 1 < nkt) {
            const short* ksrc = Kg + kqbase + (size_t)(kt + 1) * 64 * HD;
            const short* vsrc = Vg + vbase + (kt + 1) * 64;
            kreg[0] = *(const short8*)&ksrc[idx0];
            kreg[1] = *(const short8*)&ksrc[idx1];
            vreg[0] = *(const short8*)&vsrc[(size_t)row0 * SEQ + offs0];
            vreg[1] = *(const short8*)&vsrc[(size_t)row1 * SEQ + offs1];
        }

        if (kt < 2 * qt) {
            strip_step<false>(Ksh, Vsh, Psh[wave][0], aq[0], acc_o[0], lacc[0],
                              bones, col, quad, qrow0);
            strip_step<false>(Ksh, Vsh, Psh[wave][1], aq[1], acc_o[1], lacc[1],
                              bones, col, quad, qrow0);
        } else if (kt == 2 * qt) {
            strip_step<true>(Ksh, Vsh, Psh[wave][0], aq[0], acc_o[0], lacc[0],
                             bones, col, quad, qrow0);
            strip_step<false>(Ksh, Vsh, Psh[wave][1], aq[1], acc_o[1], lacc[1],
                              bones, col, quad, qrow0);
        } else {
            strip_step<true>(Ksh, Vsh, Psh[wave][1], aq[1], acc_o[1], lacc[1],
                             bones, col, quad, qrow0);
        }
    }

    #pragma unroll
    for (int st = 0; st < 2; st++) {
        #pragma unroll
        for (int r = 0; r < 4; r++) {
            float l = __shfl(lacc[st][r], quad * 16, 64);
            float inv = 1.f / l;
            int t = qt * 128 + st * 64 + wave * 16 + quad * 4 + r;
            size_t ybase = ((size_t)(b * SEQ + t)) * CH + h * HD;
            #pragma unroll
            for (int nt = 0; nt < 4; nt++)
                Y[ybase + nt * 16 + col] = f2bf(acc_o[st][nt][r] * inv);
        }
    }
}

// ---------------------------------------------------------------------------
extern "C" void kernel_launch(void* const* d_in, const int* in_sizes, int n_in,
                              void* d_out, int out_size, void* d_ws, size_t ws_size,
                              hipStream_t stream)
{
    const float* x      = (const float*)d_in[0];  // [B,T,C]
    const float* w_attn = (const float*)d_in[1];  // [C,3C]
    const float* b_attn = (const float*)d_in[2];  // [3C]
    const float* w_proj = (const float*)d_in[3];  // [C,C]
    const float* b_proj = (const float*)d_in[4];  // [C]
    float* out = (float*)d_out;                   // [B,T,C] fp32

    // workspace layout (bf16 shorts)
    short* qkv16 = (short*)d_ws;                          // 3*HSZ
    short* y16   = qkv16 + (size_t)3 * HSZ;               // HSZ   [B,T,C]
    short* xb    = y16   + (size_t)HSZ;                   // HSZ   [B*T, C]
    short* wta   = xb    + (size_t)HSZ;                   // [3C, C] = w_attn^T
    short* wtp   = wta   + (size_t)3 * CH * CH;           // [C, C]  = w_proj^T

    const int M = BATCH * SEQ;   // 8192

    // Fused prep: cast x + transpose-cast both weights (one launch)
    prep_kernel<<<NCAST + NTA + NTP, 256, 0, stream>>>(x, xb, w_attn, wta, w_proj, wtp);

    // GEMM1: qkv = x @ w_attn + b_attn -> bf16 q/k/v (v transposed)
    // round-0 config restored (best measured TOTAL): 128x192 tiles,
    // grid = 8 xcd * 8 m * 12 n = 768 = exactly 3 blocks/CU
    gemm_bt_kernel<1, 128, 192, 12, 8, 3><<<768, 256, 0, stream>>>(
        xb, wta, b_attn, qkv16, M, 3 * CH, CH);

    // Flash attention -> y16 bf16 [B,T,C]
    // 1-D grid: bid = qt*96 + bh -> same-bh q-tiles co-locate on one XCD
    attn_kernel<<<768, 256, 0, stream>>>(qkv16, qkv16 + (size_t)HSZ,
                                         qkv16 + (size_t)2 * HSZ, y16);

    // GEMM2: out = y @ w_proj + b_proj (fp32 out)
    // 128x192 tiles: grid = 8 xcd * 8 m * 4 n = 256 = 1 block/CU co-resident
    gemm_bt_kernel<0, 128, 192, 4, 8, 3><<<256, 256, 0, stream>>>(
        y16, wtp, b_proj, out, M, CH, CH);
}

// Round 7
// 171.731 us; speedup vs baseline: 1.0439x; 1.0221x over previous
//
#include <hip/hip_runtime.h>
#include <hip/hip_bf16.h>
#include <math.h>

// Problem constants (B=8, T=1024, C=768, H=12, D=64)
#define BATCH 8
#define SEQ   1024
#define CH    768
#define NH    12
#define HD    64
#define HSZ   (BATCH * NH * SEQ * HD)   // 6291456 elements = B*T*C

typedef __attribute__((ext_vector_type(8))) short short8;   // 8 bf16 = 4 VGPRs
typedef __attribute__((ext_vector_type(4))) short short4v;
typedef __attribute__((ext_vector_type(4))) float floatx4;  // MFMA C/D frag

// fp32 -> bf16 RNE
static __device__ inline short f2bf(float f) {
    union { float f; unsigned u; } x; x.f = f;
    unsigned r = (x.u + 0x7fffu + ((x.u >> 16) & 1u)) >> 16;
    return (short)r;
}

// async global->LDS, 16B per lane; LDS dest must be wave-uniform base + lane*16
#define GLOAD_LDS16(g, l)                                                     \
    __builtin_amdgcn_global_load_lds(                                         \
        (const __attribute__((address_space(1))) void*)(g),                   \
        (__attribute__((address_space(3))) void*)(l), 16, 0, 0)

// ---------------------------------------------------------------------------
// Fused prep (one launch): cast x fp32->bf16; transpose-cast w_attn and w_proj
// to bf16 [N,K]. Block role decoded from blockIdx.x.
// ---------------------------------------------------------------------------
#define NCAST (BATCH * SEQ * CH / 1024)          // 6144 blocks, 1024 elems each
#define NTA   ((3 * CH / 32) * (CH / 32))        // 1728 tiles for w_attn
#define NTP   ((CH / 32) * (CH / 32))            // 576 tiles for w_proj

__device__ __forceinline__ void transpose_tile(
    const float* __restrict__ w, short* __restrict__ wt, int K, int N,
    int bx, int by, int tid, float (*tile)[33])
{
    const int tx = tid & 31, ty = tid >> 5;      // 32 x 8
    const int n0 = bx * 32, k0 = by * 32;
    #pragma unroll
    for (int i = 0; i < 4; i++)
        tile[ty + i * 8][tx] = w[(size_t)(k0 + ty + i * 8) * N + n0 + tx];
    __syncthreads();
    #pragma unroll
    for (int i = 0; i < 4; i++)
        wt[(size_t)(n0 + ty + i * 8) * K + k0 + tx] = f2bf(tile[tx][ty + i * 8]);
}

__global__ __launch_bounds__(256) void prep_kernel(
    const float* __restrict__ x, short* __restrict__ xb,
    const float* __restrict__ wa, short* __restrict__ wta,
    const float* __restrict__ wp, short* __restrict__ wtp)
{
    __shared__ float tile[32][33];
    const int bid = blockIdx.x, tid = threadIdx.x;
    if (bid < NCAST) {
        int i = (bid * 256 + tid) * 4;
        float4 v = *(const float4*)(x + i);
        short4v o = { f2bf(v.x), f2bf(v.y), f2bf(v.z), f2bf(v.w) };
        *(short4v*)(xb + i) = o;
    } else if (bid < NCAST + NTA) {
        int t = bid - NCAST;
        transpose_tile(wa, wta, CH, 3 * CH, t % (3 * CH / 32), t / (3 * CH / 32), tid, tile);
    } else {
        int t = bid - NCAST - NTA;
        transpose_tile(wp, wtp, CH, CH, t % (CH / 32), t / (CH / 32), tid, tile);
    }
}

// ---------------------------------------------------------------------------
// bf16 MFMA GEMM (round-0 structure): C[M,N] = A[M,K] @ Bt[N,K]^T + bias[N]
//  - K-loop: global_load_lds dbuf, 1 __syncthreads per K-tile of 32,
//    XOR bank swizzle, XCD-partitioned 1D grid.
//  - MODE 1: coalesced q/k/v epilogue through LDS (q/k [bh][t][d],
//    v [bh][d][t]).  MODE 0: fp32 row-major store.
// ---------------------------------------------------------------------------
template <int MODE, int BM, int BN, int NBLK, int MBX, int WPE>
__global__ __launch_bounds__(256, WPE) void gemm_bt_kernel(
    const short* __restrict__ A, const short* __restrict__ Bt,
    const float* __restrict__ bias, void* __restrict__ outv,
    int M, int N, int K)
{
    constexpr int MT  = BM / 32;
    constexpr int NT  = BN / 32;
    constexpr int ACH = BM / 64;
    constexpr int BCH = BN / 64;
    constexpr int STAGE_BYTES = (BM + BN) * 128;              // 2 bufs x rows x 64B
    constexpr int EPI_BYTES   = (MODE == 1) ? (BN * 136 * 2) : 0;  // v layout largest
    constexpr int LDS_BYTES   = STAGE_BYTES > EPI_BYTES ? STAGE_BYTES : EPI_BYTES;
    __shared__ __align__(16) char smem[LDS_BYTES];
    short* AsB = (short*)smem;                    // 2 bufs x BM*32
    short* BsB = (short*)(smem + BM * 128);       // 2 bufs x BN*32

    const int tid  = threadIdx.x;
    const int lane = tid & 63;
    const int col  = lane & 15;
    const int quad = lane >> 4;
    const int wave = tid >> 6;
    const int wm = wave & 1, wn = wave >> 1;

    const int bid = blockIdx.x;
    const int j   = bid & 7;
    const int t   = bid >> 3;
    const int mb  = j * MBX + t / NBLK;
    const int nb  = t % NBLK;
    const int m0 = mb * BM, n0 = nb * BN;

    const int srow = tid >> 2;
    const int kc   = ((tid & 3) ^ (srow & 3)) * 8;
    const short* aptr[ACH];
    const short* bptr[BCH];
    #pragma unroll
    for (int c = 0; c < ACH; c++)
        aptr[c] = A + (size_t)(m0 + c * 64 + srow) * K + kc;
    #pragma unroll
    for (int c = 0; c < BCH; c++)
        bptr[c] = Bt + (size_t)(n0 + c * 64 + srow) * K + kc;

    floatx4 acc[MT][NT];
    #pragma unroll
    for (int i = 0; i < MT; i++)
        #pragma unroll
        for (int jj = 0; jj < NT; jj++)
            acc[i][jj] = (floatx4){0.f, 0.f, 0.f, 0.f};

    const int niter = K / 32;

    #pragma unroll
    for (int c = 0; c < ACH; c++) GLOAD_LDS16(aptr[c], &AsB[c * 2048 + tid * 8]);
    #pragma unroll
    for (int c = 0; c < BCH; c++) GLOAD_LDS16(bptr[c], &BsB[c * 2048 + tid * 8]);

    for (int k = 0; k < niter; k++) {
        __syncthreads();
        const int cur = k & 1, nxt = cur ^ 1;
        if (k + 1 < niter) {
            const int ko = (k + 1) * 32;
            #pragma unroll
            for (int c = 0; c < ACH; c++)
                GLOAD_LDS16(aptr[c] + ko, &AsB[nxt * BM * 32 + c * 2048 + tid * 8]);
            #pragma unroll
            for (int c = 0; c < BCH; c++)
                GLOAD_LDS16(bptr[c] + ko, &BsB[nxt * BN * 32 + c * 2048 + tid * 8]);
        }
        short8 af[MT], bf[NT];
        #pragma unroll
        for (int mt = 0; mt < MT; mt++) {
            const int row = wm * (BM / 2) + mt * 16 + col;
            af[mt] = *(const short8*)&AsB[cur * BM * 32 + row * 32 + ((quad ^ (row & 3)) << 3)];
        }
        #pragma unroll
        for (int nt = 0; nt < NT; nt++) {
            const int row = wn * (BN / 2) + nt * 16 + col;
            bf[nt] = *(const short8*)&BsB[cur * BN * 32 + row * 32 + ((quad ^ (row & 3)) << 3)];
        }
        #pragma unroll
        for (int mt = 0; mt < MT; mt++)
            #pragma unroll
            for (int nt = 0; nt < NT; nt++)
                acc[mt][nt] = __builtin_amdgcn_mfma_f32_16x16x32_bf16(
                    af[mt], bf[nt], acc[mt][nt], 0, 0, 0);
    }

    if constexpr (MODE == 0) {
        // fp32 row-major store (already reasonably coalesced)
        #pragma unroll
        for (int mt = 0; mt < MT; mt++) {
            #pragma unroll
            for (int r = 0; r < 4; r++) {
                const int m = m0 + wm * (BM / 2) + mt * 16 + quad * 4 + r;
                #pragma unroll
                for (int nt = 0; nt < NT; nt++) {
                    const int n = n0 + wn * (BN / 2) + nt * 16 + col;
                    ((float*)outv)[(size_t)m * N + n] = acc[mt][nt][r] + bias[n];
                }
            }
        }
    } else {
        // coalesced q/k/v epilogue through LDS
        __syncthreads();                      // staging LDS now reusable
        short* Es = (short*)smem;
        const int sel = n0 / CH;              // uniform per block (192 | 768)
        const int h0  = (n0 - sel * CH) >> 6; // first head of this 3-head slice
        const int bb  = m0 >> 10;
        const int t0  = m0 & 1023;
        short* qkv = (short*)outv;

        if (sel < 2) {
            // LDS [m][n], stride 200 (conflict-broken)
            #pragma unroll
            for (int mt = 0; mt < MT; mt++)
                #pragma unroll
                for (int r = 0; r < 4; r++) {
                    const int lm = wm * (BM / 2) + mt * 16 + quad * 4 + r;
                    #pragma unroll
                    for (int nt = 0; nt < NT; nt++) {
                        const int ln = wn * (BN / 2) + nt * 16 + col;
                        Es[lm * 200 + ln] = f2bf(acc[mt][nt][r] + bias[n0 + ln]);
                    }
                }
            __syncthreads();
            // store: 8 lanes cover one 128B t-row; contiguous across lanes
            #pragma unroll
            for (int it = 0; it < (BM * BN / 8) / 256; it++) {
                const int id = it * 256 + tid;
                const int hp = id >> 10, lm = (id >> 3) & 127, dc = id & 7;
                short8 v = *(const short8*)&Es[lm * 200 + hp * 64 + dc * 8];
                size_t dst = (size_t)sel * HSZ +
                    (((size_t)(bb * NH + h0 + hp)) * SEQ + t0 + lm) * HD + dc * 8;
                *(short8*)&qkv[dst] = v;
            }
        } else {
            // v: LDS [n][m], stride 136; b64 packed writes (r-values m-adjacent)
            #pragma unroll
            for (int nt = 0; nt < NT; nt++) {
                const int ln = wn * (BN / 2) + nt * 16 + col;
                const float bv = bias[n0 + ln];
                #pragma unroll
                for (int mt = 0; mt < MT; mt++) {
                    const int lm = wm * (BM / 2) + mt * 16 + quad * 4;
                    short4v pk;
                    #pragma unroll
                    for (int r = 0; r < 4; r++) pk[r] = f2bf(acc[mt][nt][r] + bv);
                    *(short4v*)&Es[ln * 136 + lm] = pk;
                }
            }
            __syncthreads();
            // store: 16 lanes cover 128 consecutive t per (h,d) row
            #pragma unroll
            for (int it = 0; it < (BM * BN / 8) / 256; it++) {
                const int id = it * 256 + tid;
                const int ln = id >> 4, tc = id & 15;
                short8 v = *(const short8*)&Es[ln * 136 + tc * 8];
                const int hp = ln >> 6, d = ln & 63;
                size_t dst = (size_t)2 * HSZ +
                    (((size_t)(bb * NH + h0 + hp)) * HD + d) * SEQ + t0 + tc * 8;
                *(short8*)&qkv[dst] = v;
            }
        }
    }
}

// ---------------------------------------------------------------------------
// bf16 MFMA flash attention, round-7: 8 waves x 1 strip (was 4 waves x 2).
//  - Halves each wave's serial chain {QK MFMA -> exp/write -> barrier ->
//    P read -> PV MFMA}; per-wave state halves (VGPR <= 128) so
//    __launch_bounds__(512,4) gives 16 waves/CU (was 12).
//  - LDS byte-identical (Psh[8][16*LDK] == old Psh[4][2][16*LDK]).
//  - K/V tile staged in ONE b128 store per lane (512 lanes x 16B = 8 KB tile).
//  - 1-D grid, bid = qt*96 + bh: same-bh q-tiles co-locate on one XCD;
//    per-XCD K/V footprint 12 bh x 256 KB = 3 MB < 4 MB L2 (T1 regime).
//  - Causal edge is wave-uniform: waves 0-3 hit diag at kt==2qt, waves 4-7
//    at kt==2qt+1 (waves 0-3 idle there; no __syncthreads inside branches).
// ---------------------------------------------------------------------------
#define LDK 72   // padded row length (bf16) -> 144 B stride

template <bool DIAG>
__device__ __forceinline__ void strip_step(
    const short* __restrict__ Ksh, const short* __restrict__ Vsh,
    short* __restrict__ pw, const short8* aq, floatx4* acc_o,
    floatx4& lacc, short8 bones, int col, int quad, int qrow0)
{
    floatx4 sacc[4];
    #pragma unroll
    for (int i = 0; i < 4; i++) sacc[i] = (floatx4){0.f, 0.f, 0.f, 0.f};
    #pragma unroll
    for (int s = 0; s < 2; s++)
        #pragma unroll
        for (int nt = 0; nt < 4; nt++) {
            short8 bk = *(const short8*)&Ksh[(nt * 16 + col) * LDK + s * 32 + quad * 8];
            sacc[nt] = __builtin_amdgcn_mfma_f32_16x16x32_bf16(aq[s], bk, sacc[nt], 0, 0, 0);
        }

    const float SCL = 0.18033688011112042f;   // 0.125 * log2(e)
    #pragma unroll
    for (int r = 0; r < 4; r++)
        #pragma unroll
        for (int nt = 0; nt < 4; nt++) {
            float sv = sacc[nt][r] * SCL;
            if (DIAG && (nt * 16 + col) > (qrow0 + r)) sv = -INFINITY;
            float pv = __builtin_amdgcn_exp2f(sv);
            pw[(quad * 4 + r) * LDK + nt * 16 + col] =
                (short)(__builtin_bit_cast(unsigned, pv) >> 16);
        }
    __builtin_amdgcn_wave_barrier();

    short8 ap[2];
    ap[0] = *(const short8*)&pw[col * LDK + quad * 8];
    ap[1] = *(const short8*)&pw[col * LDK + 32 + quad * 8];

    #pragma unroll
    for (int s = 0; s < 2; s++) {
        #pragma unroll
        for (int nt = 0; nt < 4; nt++) {
            short8 bv = *(const short8*)&Vsh[(nt * 16 + col) * LDK + s * 32 + quad * 8];
            acc_o[nt] = __builtin_amdgcn_mfma_f32_16x16x32_bf16(ap[s], bv, acc_o[nt], 0, 0, 0);
        }
        lacc = __builtin_amdgcn_mfma_f32_16x16x32_bf16(ap[s], bones, lacc, 0, 0, 0);
    }
}

__global__ __launch_bounds__(512, 4) void attn_kernel(
    const short* __restrict__ Qg, const short* __restrict__ Kg,
    const short* __restrict__ Vg, short* __restrict__ Y)
{
    __shared__ __align__(16) short Ksh[64 * LDK];
    __shared__ __align__(16) short Vsh[64 * LDK];     // [dim][key]
    __shared__ __align__(16) short Psh[8][16 * LDK];  // per-wave strip

    const int tid  = threadIdx.x;
    const int wave = tid >> 6;               // 0..7, one 16-row strip each
    const int lane = tid & 63;
    const int col  = lane & 15;
    const int quad = lane >> 4;
    const int bid = blockIdx.x;              // 0..767
    const int bh  = bid % 96;                // XCD = bh & 7 for ALL q-tiles of bh
    const int qt  = bid / 96;                // 128-row q-tile
    const int b = bh / NH, h = bh - b * NH;

    const size_t kqbase = (size_t)bh * SEQ * HD;   // q,k: [bh][t][d]
    const size_t vbase  = (size_t)bh * HD * SEQ;   // v:   [bh][d][t]

    short8 aq[2];
    {
        const short* qp = Qg + kqbase +
            (size_t)(qt * 128 + wave * 16 + col) * HD + quad * 8;
        aq[0] = *(const short8*)(qp);
        aq[1] = *(const short8*)(qp + 32);
    }

    floatx4 acc_o[4];
    floatx4 lacc = (floatx4){0.f, 0.f, 0.f, 0.f};
    #pragma unroll
    for (int i = 0; i < 4; i++) acc_o[i] = (floatx4){0.f, 0.f, 0.f, 0.f};

    const short one_bf = (short)0x3F80;
    short8 bones = (col == 0)
        ? (short8){one_bf, one_bf, one_bf, one_bf, one_bf, one_bf, one_bf, one_bf}
        : (short8){0, 0, 0, 0, 0, 0, 0, 0};

    const int qrow0 = (wave & 3) * 16 + quad * 4;   // row within 64-row diag tile

    const int idx = tid * 8;                 // 512 lanes x 8 shorts = full tile
    const int row = idx >> 6, offs = idx & 63;

    short8 kreg, vreg;
    {
        const short* ksrc = Kg + kqbase;
        const short* vsrc = Vg + vbase;
        kreg = *(const short8*)&ksrc[idx];
        vreg = *(const short8*)&vsrc[(size_t)row * SEQ + offs];
    }

    const int nkt = 2 * qt + 2;
    for (int kt = 0; kt < nkt; kt++) {
        __syncthreads();
        *(short8*)&Ksh[row * LDK + offs] = kreg;
        *(short8*)&Vsh[row * LDK + offs] = vreg;
        __syncthreads();

        if (kt + 1 < nkt) {
            const short* ksrc = Kg + kqbase + (size_t)(kt + 1) * 64 * HD;
            const short* vsrc = Vg + vbase + (kt + 1) * 64;
            kreg = *(const short8*)&ksrc[idx];
            vreg = *(const short8*)&vsrc[(size_t)row * SEQ + offs];
        }

        if (kt < 2 * qt) {
            strip_step<false>(Ksh, Vsh, Psh[wave], aq, acc_o, lacc,
                              bones, col, quad, qrow0);
        } else if (kt == 2 * qt) {
            if (wave < 4)
                strip_step<true>(Ksh, Vsh, Psh[wave], aq, acc_o, lacc,
                                 bones, col, quad, qrow0);
            else
                strip_step<false>(Ksh, Vsh, Psh[wave], aq, acc_o, lacc,
                                  bones, col, quad, qrow0);
        } else {
            if (wave >= 4)
                strip_step<true>(Ksh, Vsh, Psh[wave], aq, acc_o, lacc,
                                 bones, col, quad, qrow0);
            // waves 0-3 idle on the final half-tile
        }
    }

    #pragma unroll
    for (int r = 0; r < 4; r++) {
        float l = __shfl(lacc[r], quad * 16, 64);
        float inv = 1.f / l;
        int t = qt * 128 + wave * 16 + quad * 4 + r;
        size_t ybase = ((size_t)(b * SEQ + t)) * CH + h * HD;
        #pragma unroll
        for (int nt = 0; nt < 4; nt++)
            Y[ybase + nt * 16 + col] = f2bf(acc_o[nt][r] * inv);
    }
}

// ---------------------------------------------------------------------------
extern "C" void kernel_launch(void* const* d_in, const int* in_sizes, int n_in,
                              void* d_out, int out_size, void* d_ws, size_t ws_size,
                              hipStream_t stream)
{
    const float* x      = (const float*)d_in[0];  // [B,T,C]
    const float* w_attn = (const float*)d_in[1];  // [C,3C]
    const float* b_attn = (const float*)d_in[2];  // [3C]
    const float* w_proj = (const float*)d_in[3];  // [C,C]
    const float* b_proj = (const float*)d_in[4];  // [C]
    float* out = (float*)d_out;                   // [B,T,C] fp32

    // workspace layout (bf16 shorts)
    short* qkv16 = (short*)d_ws;                          // 3*HSZ
    short* y16   = qkv16 + (size_t)3 * HSZ;               // HSZ   [B,T,C]
    short* xb    = y16   + (size_t)HSZ;                   // HSZ   [B*T, C]
    short* wta   = xb    + (size_t)HSZ;                   // [3C, C] = w_attn^T
    short* wtp   = wta   + (size_t)3 * CH * CH;           // [C, C]  = w_proj^T

    const int M = BATCH * SEQ;   // 8192

    // Fused prep: cast x + transpose-cast both weights (one launch)
    prep_kernel<<<NCAST + NTA + NTP, 256, 0, stream>>>(x, xb, w_attn, wta, w_proj, wtp);

    // GEMM1: qkv = x @ w_attn + b_attn -> bf16 q/k/v (v transposed)
    // round-0 config (best measured at healthy clock): 128x192 tiles,
    // grid = 8 xcd * 8 m * 12 n = 768 = exactly 3 blocks/CU
    gemm_bt_kernel<1, 128, 192, 12, 8, 3><<<768, 256, 0, stream>>>(
        xb, wta, b_attn, qkv16, M, 3 * CH, CH);

    // Flash attention -> y16 bf16 [B,T,C]; 8-wave strips, L2-local 1-D grid
    attn_kernel<<<768, 512, 0, stream>>>(qkv16, qkv16 + (size_t)HSZ,
                                         qkv16 + (size_t)2 * HSZ, y16);

    // GEMM2: out = y @ w_proj + b_proj (fp32 out)
    // round-0 config: 64x192 tiles, grid = 8 xcd * 16 m * 4 n = 512 = 2/CU
    gemm_bt_kernel<0, 64, 192, 4, 16, 4><<<512, 256, 0, stream>>>(
        y16, wtp, b_proj, out, M, CH, CH);
}